// Round 1
// baseline (424.977 us; speedup 1.0000x reference)
//
#include <hip/hip_runtime.h>

#pragma clang fp contract(off)

#define TOLD 60000
#define TNEW 60000
#define NVERT 30000
#define MAXSTEPS 300
#define THSZ 131072                  // tet-key hash slots (exact, CAS)
#define FHSZ 131072                  // exact CAS face table (DM-collision fallback only)
#define EMPTY64 0xFFFFFFFFFFFFFFFFULL

// Single persistent kernel: 768 blocks x 256 thr, __launch_bounds__(256,3)
// guarantees 3 blocks/CU x 256 CUs = 768 co-resident -> manual grid barrier
// is deadlock-free by construction.
#define GRID_NB 768

// virtual-block counts per phase
#define NB_SETUP 235                 // ceil(60000/256)
#define NB_NEWG  235
#define NB_FACE  938                 // ceil(240000/256)
#define NB_MATCH 235
#define NB_FB    120                 // fallback blocks (scan 500 walkers each)
#define FBRANGE  (TNEW / NB_FB)      // 500

// workspace layout: [0xFF-init region][rest, no init needed]
#define OFF_TKEYS    0u              // 131072*8 = 1,048,576
#define OFF_FTAB     1048576u        // 131072*8 = 1,048,576
#define OFF_NBR      2097152u        // 240000*4 =   960,000
#define OFF_PRIO     3057152u        // 30000*4  =   120,000 (0xFF = -1 init; atomicMax target)
#define OFF_BAR      3177152u        // 64 B barrier words (count=-1, gen=-1 via 0xFF)
#define FF_BYTES     3177216u        // end of 0xFF region
#define OFF_CNT      3177216u        // 2048 B: counters[0..63] + hist[64..365] (zeroed by P1 blk0)
#define OFF_TVALS    3179264u        // 524,288 (poison-safe)
#define OFF_IDXOLD   3703552u        // 960,000 (16B aligned)
#define OFF_SSTEP    4663552u        // 240,000 (settle step per walker; only read when matched<0)
#define OFF_DEGEN    4903552u        // 240,000
#define OFF_MATCHED  5143552u        // 240,000
#define OFF_TV4      5383552u        // 2,880,000 (3 float4/tet: Tinv row + v0 comp)
#define OFF_COLD4    8263552u        // 960,000 (centroid, oel)
#define OFF_CNEW4    9223552u        // 960,000 (centroid, nel)
#define OFF_DM       10183552u       // 64-bit keyed DM face table (uninit/poison-safe)

struct P {
  const unsigned int* rawNew;
  const unsigned int* rawOld;
  const float* occ;
  const float* ncc;
  const float* verts;
  float* out;
  unsigned long long* tkeys;
  unsigned long long* ftab;
  int* counters;   // [0]=n_walk; [64..365]=hist[s] (settle-step histogram)
  int* tvals;
  int* idxOld;
  int* nbr;
  int* prio;       // direct atomicMax target, init -1 via 0xFF memset
  int* sstep;
  int* degen;
  int* matched;
  float4* Tv4;
  float4* cold4;
  float4* cnew4;
  unsigned long long* dm;            // (key<<18 | tet*4+local), racy last-wins
  int* bar;                          // [0]=count(init -1), [1]=gen(init -1)
  unsigned int dmMask;
};

__device__ __forceinline__ unsigned hash64(unsigned long long k){
  k ^= k >> 33; k *= 0xff51afd7ed558ccdULL;
  k ^= k >> 33; k *= 0xc4ceb9fe1a85ec53ULL;
  k ^= k >> 33;
  return (unsigned)k;
}
__device__ __forceinline__ void cswap(int& a, int& b){ if (a > b){ int t = a; a = b; b = t; } }

__device__ __forceinline__ int detect64(const unsigned int* raw){
  unsigned acc = 0;
  const uint4* r4 = (const uint4*)raw;
  #pragma unroll
  for (int k = 0; k < 32; ++k){ uint4 v = r4[k]; acc |= (v.y | v.w); }
  return acc == 0u;
}

__device__ __forceinline__ int4 load_tet4(const unsigned int* raw, int is64, int t){
  if (is64){
    uint4 a = ((const uint4*)raw)[t * 2 + 0];
    uint4 b = ((const uint4*)raw)[t * 2 + 1];
    return make_int4((int)a.x, (int)a.z, (int)b.x, (int)b.z);
  }
  uint4 a = ((const uint4*)raw)[t];
  return make_int4((int)a.x, (int)a.y, (int)a.z, (int)a.w);
}

__device__ __forceinline__ void face_insert(unsigned long long* ftab, int* nbr,
                                            unsigned long long fkey, int t, int l){
  unsigned long long mine = (fkey << 18) | (unsigned long long)(t * 4 + l);
  unsigned slot = hash64(fkey ^ 0x9e3779b97f4a7c15ULL) & (FHSZ - 1);
  while (true){
    unsigned long long prev = atomicCAS(&ftab[slot], EMPTY64, mine);
    if (prev == EMPTY64) return;
    if ((prev >> 18) == fkey){
      int oid = (int)(prev & 0x3FFFFULL);
      nbr[t * 4 + l] = oid >> 2;
      nbr[oid] = t;
      return;
    }
    slot = (slot + 1) & (FHSZ - 1);
  }
}

__device__ __forceinline__ float min_edge_r(
    float q0x, float q0y, float q0z, float q1x, float q1y, float q1z,
    float q2x, float q2y, float q2z, float q3x, float q3y, float q3z){
  float m = 3.402823466e+38f;
  float dx, dy, dz, d;
  dx = q0x - q1x; dy = q0y - q1y; dz = q0z - q1z; d = sqrtf((dx*dx + dy*dy) + dz*dz); m = fminf(m, d);
  dx = q0x - q2x; dy = q0y - q2y; dz = q0z - q2z; d = sqrtf((dx*dx + dy*dy) + dz*dz); m = fminf(m, d);
  dx = q0x - q3x; dy = q0y - q3y; dz = q0z - q3z; d = sqrtf((dx*dx + dy*dy) + dz*dz); m = fminf(m, d);
  dx = q1x - q2x; dy = q1y - q2y; dz = q1z - q2z; d = sqrtf((dx*dx + dy*dy) + dz*dz); m = fminf(m, d);
  dx = q1x - q3x; dy = q1y - q3y; dz = q1z - q3z; d = sqrtf((dx*dx + dy*dy) + dz*dz); m = fminf(m, d);
  dx = q2x - q3x; dy = q2y - q3y; dz = q2z - q3z; d = sqrtf((dx*dx + dy*dy) + dz*dz); m = fminf(m, d);
  return m;
}

// Device-scope sense-reversal grid barrier. Safe iff all GRID_NB blocks are
// resident (guaranteed by __launch_bounds__(256,3) and GRID_NB = 3*256).
// 0xFF memset gives count=-1, gen=-1: arrivals return -1..GRID_NB-2, so the
// last arrival sees v == GRID_NB-2. Agent-scope atomics + __threadfence give
// cross-XCD visibility (wbL2 on arrival, inv after release).
__device__ __forceinline__ void gridbar(int* bar){
  __syncthreads();
  if (threadIdx.x == 0){
    __threadfence();                                   // flush this CU/XCD's writes
    int g = __hip_atomic_load(&bar[1], __ATOMIC_ACQUIRE, __HIP_MEMORY_SCOPE_AGENT);
    int v = __hip_atomic_fetch_add(&bar[0], 1, __ATOMIC_ACQ_REL, __HIP_MEMORY_SCOPE_AGENT);
    if (v == GRID_NB - 2){
      __hip_atomic_fetch_add(&bar[0], -GRID_NB, __ATOMIC_RELAXED, __HIP_MEMORY_SCOPE_AGENT); // reset to -1
      __threadfence();
      __hip_atomic_fetch_add(&bar[1], 1, __ATOMIC_RELEASE, __HIP_MEMORY_SCOPE_AGENT);        // release
    } else {
      while (__hip_atomic_load(&bar[1], __ATOMIC_RELAXED, __HIP_MEMORY_SCOPE_AGENT) == g){
        __builtin_amdgcn_s_sleep(1);
      }
    }
    __threadfence();                                   // invalidate stale cache for reads
  }
  __syncthreads();
}

// Per-walker output assembly. Fast path when all 5 candidates coincide.
__device__ __forceinline__ void assemble_walker(const P& p, int n, int m, int remap){
  int cds[5];
  if (m >= 0){
    cds[0] = cds[1] = cds[2] = cds[3] = cds[4] = m;
  } else {
    cds[0] = remap;
    int dg = p.degen[remap];
    int4 nb4 = ((const int4*)p.nbr)[remap];
    int nbl[4] = {nb4.x, nb4.y, nb4.z, nb4.w};
    for (int l = 0; l < 4; ++l){
      int fb = dg ? -1 : nbl[l];
      cds[1 + l] = (fb >= 0) ? fb : remap;
    }
  }
  bool same = (cds[1] == cds[0]) & (cds[2] == cds[0]) &
              (cds[3] == cds[0]) & (cds[4] == cds[0]);
  int is64 = detect64(p.rawNew);
  int4 ni = load_tet4(p.rawNew, is64, n);
  float nc0 = p.ncc[n * 3 + 0], nc1 = p.ncc[n * 3 + 1], nc2 = p.ncc[n * 3 + 2];
  float nelv = fmaxf(p.cnew4[n].w, 1e-8f);
  if (same){
    int ct = cds[0];
    int4 cv = ((const int4*)p.idxOld)[ct];
    int ov = 0;
    ov += (cv.x == ni.x || cv.x == ni.y || cv.x == ni.z || cv.x == ni.w) ? 1 : 0;
    ov += (cv.y == ni.x || cv.y == ni.y || cv.y == ni.z || cv.y == ni.w) ? 1 : 0;
    ov += (cv.z == ni.x || cv.z == ni.y || cv.z == ni.z || cv.z == ni.w) ? 1 : 0;
    ov += (cv.w == ni.x || cv.w == ni.y || cv.w == ni.z || cv.w == ni.w) ? 1 : 0;
    float d0 = p.occ[ct * 3 + 0] - nc0;
    float d1 = p.occ[ct * 3 + 1] - nc1;
    float d2 = p.occ[ct * 3 + 2] - nc2;
    float ccd2 = (d0 * d0 + d1 * d1) + d2 * d2;
    float raw = expf((float)ov * 2.0f) / (ccd2 + 1e-8f);
    float rsum = 0.0f;
    rsum += raw; rsum += raw; rsum += raw; rsum += raw; rsum += raw;
    float wgt = raw / rsum;
    float ds = p.cold4[ct].w / nelv;
    ds = fminf(fmaxf(ds, 0.1f), 10.0f);
    float cf = (float)ct;
    for (int c = 0; c < 5; ++c){
      p.out[n * 5 + c] = cf;
      p.out[TNEW * 5 + n * 5 + c] = wgt;
      p.out[2 * TNEW * 5 + n * 5 + c] = ds;
    }
    return;
  }
  float raws[5]; float rsum = 0.0f;
  float oels[5];
  for (int c = 0; c < 5; ++c){
    int ct = cds[c];
    int4 cv = ((const int4*)p.idxOld)[ct];
    int ov = 0;
    ov += (cv.x == ni.x || cv.x == ni.y || cv.x == ni.z || cv.x == ni.w) ? 1 : 0;
    ov += (cv.y == ni.x || cv.y == ni.y || cv.y == ni.z || cv.y == ni.w) ? 1 : 0;
    ov += (cv.z == ni.x || cv.z == ni.y || cv.z == ni.z || cv.z == ni.w) ? 1 : 0;
    ov += (cv.w == ni.x || cv.w == ni.y || cv.w == ni.z || cv.w == ni.w) ? 1 : 0;
    float d0 = p.occ[ct * 3 + 0] - nc0;
    float d1 = p.occ[ct * 3 + 1] - nc1;
    float d2 = p.occ[ct * 3 + 2] - nc2;
    float ccd2 = (d0 * d0 + d1 * d1) + d2 * d2;
    float raw = expf((float)ov * 2.0f) / (ccd2 + 1e-8f);
    raws[c] = raw; rsum += raw;
    oels[c] = p.cold4[ct].w;
  }
  for (int c = 0; c < 5; ++c){
    p.out[n * 5 + c] = (float)cds[c];
    p.out[TNEW * 5 + n * 5 + c] = raws[c] / rsum;
    float ds = oels[c] / nelv;
    ds = fminf(fmaxf(ds, 0.1f), 10.0f);
    p.out[2 * TNEW * 5 + n * 5 + c] = ds;
  }
}

// Exact loop-exit step from the settle-step histogram:
// count_k = nw - sum_{j<=k} hist[j]; S = first k in [0,300] with count_k < thr
// (thr = max(100, nw/1000)), else 300 (MAXSTEPS bound).
__device__ __forceinline__ int compute_S(const int* counters){
  int nw = counters[0];
  int thr = max(100, nw / 1000);
  if (nw < thr) return 0;
  int cnt = nw;
  for (int k = 1; k <= MAXSTEPS; ++k){
    cnt -= counters[64 + k];
    if (cnt < thr) return k;
  }
  return MAXSTEPS;
}

// One persistent kernel, 4 phases separated by grid barriers:
//  P1: old-tet setup (Tinv, centroids, tet-key CAS, DM face writes, direct
//      atomicMax vertex prio) + new-tet geometry
//  P2: face resolve (DM verify + CAS fallback) + new-tet match probe
//  P3: per-walker local walk + LDS histogram + speculative full assembly
//  P4: repair pass (derive S; overwrite rows owned by the fallback set)
__global__ __launch_bounds__(256, 3) void k_fused(P p){
  __shared__ int s_hist[MAXSTEPS + 2];               // bins 0..301
  __shared__ int s_nw;
  __shared__ float sd[256];
  __shared__ int si[256];
  __shared__ int s_hits[256];
  __shared__ int s_nhits;
  __shared__ int s_S;

  const int bb = blockIdx.x;

  // ---------------- Phase 1 ----------------
  if (bb < NB_SETUP){
    if (bb == 0){
      for (int j = threadIdx.x; j < 384; j += 256) p.counters[j] = 0;
    }
    int t = bb * 256 + threadIdx.x;
    if (t < TOLD){
      int is64 = detect64(p.rawOld);
      int4 iv4 = load_tet4(p.rawOld, is64, t);
      int i0 = iv4.x, i1 = iv4.y, i2 = iv4.z, i3 = iv4.w;
      ((int4*)p.idxOld)[t] = iv4;

      // direct vertex-prio atomics (prio init -1 via 0xFF; values >= 0 win)
      atomicMax(&p.prio[i0], 0 * TOLD + t);
      atomicMax(&p.prio[i1], 1 * TOLD + t);
      atomicMax(&p.prio[i2], 2 * TOLD + t);
      atomicMax(&p.prio[i3], 3 * TOLD + t);

      // tet key insert; CAS winner plain-stores value, dup-key path (P~5e-8)
      // uses atomicMax. tvals poison (negative) always loses the max.
      {
        int s0 = i0, s1 = i1, s2 = i2, s3 = i3;
        cswap(s0, s1); cswap(s2, s3); cswap(s0, s2); cswap(s1, s3); cswap(s1, s2);
        unsigned long long key =
            (unsigned long long)((((long long)s0 * NVERT + s1) * NVERT + s2) * NVERT + s3);
        unsigned slot = hash64(key) & (THSZ - 1);
        while (true){
          unsigned long long prev = atomicCAS(&p.tkeys[slot], EMPTY64, key);
          if (prev == EMPTY64){ p.tvals[slot] = t; break; }
          if (prev == key){ atomicMax(&p.tvals[slot], t); break; }
          slot = (slot + 1) & (THSZ - 1);
        }
      }

      // 64-bit keyed DM face writes (racy last-wins; resolved in Phase 2)
      if (p.dmMask){
        const int FO[4][3] = {{1, 2, 3}, {0, 2, 3}, {0, 1, 3}, {0, 1, 2}};
        int iv[4] = {i0, i1, i2, i3};
        #pragma unroll
        for (int l = 0; l < 4; ++l){
          int a = iv[FO[l][0]], b = iv[FO[l][1]], c = iv[FO[l][2]];
          cswap(a, b); cswap(a, c); cswap(b, c);
          unsigned long long fk = (unsigned long long)(((long long)a * NVERT + b) * NVERT + c);
          p.dm[hash64(fk) & p.dmMask] = (fk << 18) | (unsigned long long)(t * 4 + l);
        }
      }

      float q0x = p.verts[i0 * 3 + 0], q0y = p.verts[i0 * 3 + 1], q0z = p.verts[i0 * 3 + 2];
      float q1x = p.verts[i1 * 3 + 0], q1y = p.verts[i1 * 3 + 1], q1z = p.verts[i1 * 3 + 2];
      float q2x = p.verts[i2 * 3 + 0], q2y = p.verts[i2 * 3 + 1], q2z = p.verts[i2 * 3 + 2];
      float q3x = p.verts[i3 * 3 + 0], q3y = p.verts[i3 * 3 + 1], q3z = p.verts[i3 * 3 + 2];
      float e1x = q1x - q0x, e1y = q1y - q0y, e1z = q1z - q0z;
      float e2x = q2x - q0x, e2y = q2y - q0y, e2z = q2z - q0z;
      float e3x = q3x - q0x, e3y = q3y - q0y, e3z = q3z - q0z;
      float c23x = e2y * e3z - e2z * e3y;
      float c23y = e2z * e3x - e2x * e3z;
      float c23z = e2x * e3y - e2y * e3x;
      float det = e1x * c23x + e1y * c23y + e1z * c23z;
      int dg = (fabsf(det) < 1e-10f) ? 1 : 0;
      p.degen[t] = dg;
      float4 r0, r1, r2;
      if (dg){
        r0 = make_float4(1.f, 0.f, 0.f, q0x);
        r1 = make_float4(0.f, 1.f, 0.f, q0y);
        r2 = make_float4(0.f, 0.f, 1.f, q0z);
      } else {
        float inv = 1.0f / det;
        float c31x = e3y * e1z - e3z * e1y;
        float c31y = e3z * e1x - e3x * e1z;
        float c31z = e3x * e1y - e3y * e1x;
        float c12x = e1y * e2z - e1z * e2y;
        float c12y = e1z * e2x - e1x * e2z;
        float c12z = e1x * e2y - e1y * e2x;
        r0 = make_float4(c23x * inv, c23y * inv, c23z * inv, q0x);
        r1 = make_float4(c31x * inv, c31y * inv, c31z * inv, q0y);
        r2 = make_float4(c12x * inv, c12y * inv, c12z * inv, q0z);
      }
      p.Tv4[t * 3 + 0] = r0;
      p.Tv4[t * 3 + 1] = r1;
      p.Tv4[t * 3 + 2] = r2;
      float el = min_edge_r(q0x, q0y, q0z, q1x, q1y, q1z, q2x, q2y, q2z, q3x, q3y, q3z);
      p.cold4[t] = make_float4((((q0x + q1x) + q2x) + q3x) * 0.25f,
                               (((q0y + q1y) + q2y) + q3y) * 0.25f,
                               (((q0z + q1z) + q2z) + q3z) * 0.25f, el);
    }
  } else if (bb < NB_SETUP + NB_NEWG){
    int n = (bb - NB_SETUP) * 256 + threadIdx.x;
    if (n < TNEW){
      int is64 = detect64(p.rawNew);
      int4 ni = load_tet4(p.rawNew, is64, n);
      float q0x = p.verts[ni.x * 3 + 0], q0y = p.verts[ni.x * 3 + 1], q0z = p.verts[ni.x * 3 + 2];
      float q1x = p.verts[ni.y * 3 + 0], q1y = p.verts[ni.y * 3 + 1], q1z = p.verts[ni.y * 3 + 2];
      float q2x = p.verts[ni.z * 3 + 0], q2y = p.verts[ni.z * 3 + 1], q2z = p.verts[ni.z * 3 + 2];
      float q3x = p.verts[ni.w * 3 + 0], q3y = p.verts[ni.w * 3 + 1], q3z = p.verts[ni.w * 3 + 2];
      float el = min_edge_r(q0x, q0y, q0z, q1x, q1y, q1z, q2x, q2y, q2z, q3x, q3y, q3z);
      p.cnew4[n] = make_float4((((q0x + q1x) + q2x) + q3x) * 0.25f,
                               (((q0y + q1y) + q2y) + q3y) * 0.25f,
                               (((q0z + q1z) + q2z) + q3z) * 0.25f, el);
    }
  }
  gridbar(p.bar);

  // ---------------- Phase 2 ----------------
  for (int vb = bb; vb < NB_FACE + NB_MATCH; vb += GRID_NB){
    if (vb < NB_FACE){
      int i = vb * 256 + threadIdx.x;
      if (i < TOLD * 4){
        int t = i >> 2, l = i & 3;
        int4 iv4 = ((const int4*)p.idxOld)[t];
        int iv[4] = {iv4.x, iv4.y, iv4.z, iv4.w};
        const int FO[4][3] = {{1, 2, 3}, {0, 2, 3}, {0, 1, 3}, {0, 1, 2}};
        int a = iv[FO[l][0]], b = iv[FO[l][1]], c = iv[FO[l][2]];
        cswap(a, b); cswap(a, c); cswap(b, c);
        unsigned long long fk = (unsigned long long)(((long long)a * NVERT + b) * NVERT + c);
        bool done = false;
        if (p.dmMask){
          unsigned long long mine = (fk << 18) | (unsigned long long)i;
          unsigned long long got = p.dm[hash64(fk) & p.dmMask];
          if (got == mine){
            done = true;                             // self-winner; partner links both
          } else if ((got >> 18) == fk){             // key-verified partner
            int wid = (int)(got & 0x3FFFFULL);
            p.nbr[i] = wid >> 2;
            p.nbr[wid] = t;
            done = true;
          }
        }
        if (!done) face_insert(p.ftab, p.nbr, fk, t, l);   // bucket collision: exact CAS
      }
    } else {
      int n = (vb - NB_FACE) * 256 + threadIdx.x;
      if (n < TNEW){
        int is64 = detect64(p.rawNew);
        int4 ni = load_tet4(p.rawNew, is64, n);
        int s0 = ni.x, s1 = ni.y, s2 = ni.z, s3 = ni.w;
        cswap(s0, s1); cswap(s2, s3); cswap(s0, s2); cswap(s1, s3); cswap(s1, s2);
        unsigned long long key =
            (unsigned long long)((((long long)s0 * NVERT + s1) * NVERT + s2) * NVERT + s3);
        int m = -1;
        unsigned slot = hash64(key) & (THSZ - 1);
        while (true){
          unsigned long long k = p.tkeys[slot];
          if (k == EMPTY64) break;
          if (k == key){ m = p.tvals[slot]; break; }
          slot = (slot + 1) & (THSZ - 1);
        }
        p.matched[n] = m;
      }
    }
  }
  gridbar(p.bar);

  // ---------------- Phase 3 ----------------
  // A walker's output depends on the global stop-step S only via the partition
  // settled(s<=S) vs fallback(s>S); assemble as-if settled here (matched
  // walkers have no S dependence at all); Phase 4 repairs the (normally empty)
  // fallback set by overwriting those rows after the grid barrier.
  for (int j = threadIdx.x; j < MAXSTEPS + 2; j += 256) s_hist[j] = 0;
  if (threadIdx.x == 0) s_nw = 0;
  __syncthreads();
  {
    int n = bb * 256 + threadIdx.x;
    if (n < TNEW){
      int m = p.matched[n];
      if (m >= 0){
        assemble_walker(p, n, m, 0);                 // exact; S-independent
      } else {
        atomicAdd(&s_nw, 1);                         // LDS
        int is64 = detect64(p.rawNew);
        int i0 = is64 ? (int)((const long long*)p.rawNew)[n * 4] : ((const int*)p.rawNew)[n * 4];
        int pr = p.prio[i0];
        int c = (pr >= 0) ? (pr % TOLD) : 0;         // seed
        float4 cn = p.cnew4[n];
        int s = MAXSTEPS + 1;                        // 301 = never settles
        for (int k = 1; k <= MAXSTEPS; ++k){
          float4 r0 = p.Tv4[c * 3 + 0];
          float4 r1 = p.Tv4[c * 3 + 1];
          float4 r2 = p.Tv4[c * 3 + 2];
          float rx = cn.x - r0.w, ry = cn.y - r1.w, rz = cn.z - r2.w;
          float b0 = r0.x * rx + r0.y * ry + r0.z * rz;
          float b1 = r1.x * rx + r1.y * ry + r1.z * rz;
          float b2 = r2.x * rx + r2.y * ry + r2.z * rz;
          float a0 = 1.0f - (b0 + b1 + b2);
          float ab[4] = {a0, b0, b1, b2};
          int amin = 0; float mn = ab[0];
          for (int j = 1; j < 4; ++j){ if (ab[j] < mn){ mn = ab[j]; amin = j; } }
          if (mn >= -0.0001f){ s = k; break; }                  // converged
          int nb = p.degen[c] ? -1 : p.nbr[c * 4 + amin];
          if (nb < 0){ s = k; break; }                          // boundary
          c = nb;
        }
        p.sstep[n] = s;
        atomicAdd(&s_hist[s], 1);                    // LDS
        assemble_walker(p, n, -1, c);                // speculative (settled c)
      }
    }
  }
  __syncthreads();
  if (threadIdx.x == 0 && s_nw) atomicAdd(&p.counters[0], s_nw);
  for (int j = threadIdx.x; j < MAXSTEPS + 2; j += 256){
    int v = s_hist[j];
    if (v) atomicAdd(&p.counters[64 + j], v);        // ~1-2 nonzero bins/block
  }
  gridbar(p.bar);

  // ---------------- Phase 4 ----------------
  if (bb < NB_FB){
    if (threadIdx.x == 0) s_S = compute_S(p.counters);
    __syncthreads();
    int S = s_S;
    int base = bb * FBRANGE;
    for (int chunk = base; chunk < base + FBRANGE; chunk += 256){
      if (threadIdx.x == 0) s_nhits = 0;
      __syncthreads();
      int n = chunk + threadIdx.x;
      if (n < base + FBRANGE && n < TNEW){
        if (p.matched[n] < 0 && p.sstep[n] > S)
          s_hits[atomicAdd(&s_nhits, 1)] = n;
      }
      __syncthreads();
      int nh = s_nhits;
      for (int h = 0; h < nh; ++h){
        int n2 = s_hits[h];
        float4 cn = p.cnew4[n2];
        float cx = cn.x, cy = cn.y, cz = cn.z;
        float p2 = (cx * cx + cy * cy) + cz * cz;
        float bd = 3.402823466e+38f; int bi = 0;
        for (int j = threadIdx.x; j < TOLD; j += 256){
          float4 oc = p.cold4[j];
          float dot = (cx * oc.x + cy * oc.y) + cz * oc.z;
          float c2 = (oc.x * oc.x + oc.y * oc.y) + oc.z * oc.z;
          float d = (p2 - 2.0f * dot) + c2;
          if (d < bd || (d == bd && j < bi)){ bd = d; bi = j; }
        }
        sd[threadIdx.x] = bd; si[threadIdx.x] = bi;
        __syncthreads();
        for (int s = 128; s > 0; s >>= 1){
          if ((int)threadIdx.x < s){
            float od = sd[threadIdx.x + s]; int oi = si[threadIdx.x + s];
            if (od < sd[threadIdx.x] || (od == sd[threadIdx.x] && oi < si[threadIdx.x])){
              sd[threadIdx.x] = od; si[threadIdx.x] = oi;
            }
          }
          __syncthreads();
        }
        if (threadIdx.x == 0){
          int r = si[0];
          if (r < 0) r = 0; if (r > TOLD - 1) r = TOLD - 1;
          assemble_walker(p, n2, -1, r);
        }
        __syncthreads();
      }
      __syncthreads();
    }
  }
}

extern "C" void kernel_launch(void* const* d_in, const int* in_sizes, int n_in,
                              void* d_out, int out_size, void* d_ws, size_t ws_size,
                              hipStream_t stream) {
  char* w = (char*)d_ws;
  P p;
  p.rawNew = (const unsigned int*)d_in[0];
  p.rawOld = (const unsigned int*)d_in[1];
  p.occ    = (const float*)d_in[2];
  p.ncc    = (const float*)d_in[3];
  p.verts  = (const float*)d_in[4];
  p.out    = (float*)d_out;
  p.tkeys    = (unsigned long long*)(w + OFF_TKEYS);
  p.ftab     = (unsigned long long*)(w + OFF_FTAB);
  p.nbr      = (int*)(w + OFF_NBR);
  p.prio     = (int*)(w + OFF_PRIO);
  p.bar      = (int*)(w + OFF_BAR);
  p.counters = (int*)(w + OFF_CNT);
  p.tvals    = (int*)(w + OFF_TVALS);
  p.idxOld   = (int*)(w + OFF_IDXOLD);
  p.sstep    = (int*)(w + OFF_SSTEP);
  p.degen    = (int*)(w + OFF_DEGEN);
  p.matched  = (int*)(w + OFF_MATCHED);
  p.Tv4      = (float4*)(w + OFF_TV4);
  p.cold4    = (float4*)(w + OFF_COLD4);
  p.cnew4    = (float4*)(w + OFF_CNEW4);
  p.dm       = (unsigned long long*)(w + OFF_DM);
  size_t avail = (ws_size > (size_t)OFF_DM) ? ws_size - (size_t)OFF_DM : 0;
  unsigned dmMask = 0;
  for (int bshift = 21; bshift >= 16; --bshift){
    if (avail >= ((size_t)8 << bshift)){ dmMask = (1u << bshift) - 1u; break; }
  }
  p.dmMask = dmMask;

  hipMemsetAsync(w, 0xFF, FF_BYTES, stream);
  hipLaunchKernelGGL(k_fused, dim3(GRID_NB), dim3(256), 0, stream, p);
}

// Round 3
// 116.521 us; speedup vs baseline: 3.6472x; 3.6472x over previous
//
#include <hip/hip_runtime.h>

#pragma clang fp contract(off)

#define TOLD 60000
#define TNEW 60000
#define NVERT 30000
#define MAXSTEPS 300
#define THSZ 131072                  // tet-key hash slots (exact, CAS)
#define FHSZ 131072                  // exact CAS face table (DM-collision fallback only)
#define EMPTY64 0xFFFFFFFFFFFFFFFFULL

// K1 block-range split
#define NB_SETUP 235                 // ceil(60000/256)
#define NB_NEWG  235
// K2 block-range split
#define NB_FACE  938                 // ceil(240000/256)
#define NB_MATCH 235                 // tet-match probe for new tets
// K_tail: repair-only pass
#define NB_FB    120                 // fallback blocks (scan 500 walkers each)
#define FBRANGE  (TNEW / NB_FB)      // 500

// workspace layout: [0xFF-init region][rest, no init needed]
#define OFF_TKEYS    0u              // 131072*8 = 1,048,576
#define OFF_FTAB     1048576u        // 131072*8 = 1,048,576
#define OFF_NBR      2097152u        // 240000*4 =   960,000
#define OFF_PRIO     3057152u        // 30000*4  =   120,000 (0xFF = -1; direct atomicMax target)
#define FF_BYTES     3177152u        // end of 0xFF region
#define OFF_CNT      3177152u        // 2048 B: counters[0..63] + hist[64..365] (zeroed by k_front blk0)
#define OFF_TVALS    3179200u        // 524,288 (poison-safe)
#define OFF_IDXOLD   3703552u        // 960,000 (16B aligned: 3,703,552 = 16*231,472)
#define OFF_SSTEP    4663552u        // 240,000 (settle step per walker; only read when matched<0)
#define OFF_DEGEN    4903552u        // 240,000
#define OFF_MATCHED  5143552u        // 240,000
#define OFF_TV4      5383552u        // 2,880,000 (3 float4/tet: Tinv row + v0 comp)
#define OFF_COLD4    8263552u        // 960,000 (centroid, oel)
#define OFF_CNEW4    9223552u        // 960,000 (centroid, nel)
#define OFF_DM       10183552u       // 64-bit keyed DM face table (uninit/poison-safe)

struct P {
  const unsigned int* rawNew;
  const unsigned int* rawOld;
  const float* occ;
  const float* ncc;
  const float* verts;
  float* out;
  unsigned long long* tkeys;
  unsigned long long* ftab;
  int* counters;   // [0]=n_walk; [64..365]=hist[s] (settle-step histogram)
  int* tvals;
  int* idxOld;
  int* nbr;
  int* prio;       // direct atomicMax target, init -1 via 0xFF memset
  int* sstep;
  int* degen;
  int* matched;
  float4* Tv4;
  float4* cold4;
  float4* cnew4;
  unsigned long long* dm;            // (key<<18 | tet*4+local), racy last-wins
  unsigned int dmMask;
};

__device__ __forceinline__ unsigned hash64(unsigned long long k){
  k ^= k >> 33; k *= 0xff51afd7ed558ccdULL;
  k ^= k >> 33; k *= 0xc4ceb9fe1a85ec53ULL;
  k ^= k >> 33;
  return (unsigned)k;
}
__device__ __forceinline__ void cswap(int& a, int& b){ if (a > b){ int t = a; a = b; b = t; } }

__device__ __forceinline__ int detect64(const unsigned int* raw){
  unsigned acc = 0;
  const uint4* r4 = (const uint4*)raw;
  #pragma unroll
  for (int k = 0; k < 32; ++k){ uint4 v = r4[k]; acc |= (v.y | v.w); }
  return acc == 0u;
}

__device__ __forceinline__ int4 load_tet4(const unsigned int* raw, int is64, int t){
  if (is64){
    uint4 a = ((const uint4*)raw)[t * 2 + 0];
    uint4 b = ((const uint4*)raw)[t * 2 + 1];
    return make_int4((int)a.x, (int)a.z, (int)b.x, (int)b.z);
  }
  uint4 a = ((const uint4*)raw)[t];
  return make_int4((int)a.x, (int)a.y, (int)a.z, (int)a.w);
}

__device__ __forceinline__ void face_insert(unsigned long long* ftab, int* nbr,
                                            unsigned long long fkey, int t, int l){
  unsigned long long mine = (fkey << 18) | (unsigned long long)(t * 4 + l);
  unsigned slot = hash64(fkey ^ 0x9e3779b97f4a7c15ULL) & (FHSZ - 1);
  while (true){
    unsigned long long prev = atomicCAS(&ftab[slot], EMPTY64, mine);
    if (prev == EMPTY64) return;
    if ((prev >> 18) == fkey){
      int oid = (int)(prev & 0x3FFFFULL);
      nbr[t * 4 + l] = oid >> 2;
      nbr[oid] = t;
      return;
    }
    slot = (slot + 1) & (FHSZ - 1);
  }
}

__device__ __forceinline__ float min_edge_r(
    float q0x, float q0y, float q0z, float q1x, float q1y, float q1z,
    float q2x, float q2y, float q2z, float q3x, float q3y, float q3z){
  float m = 3.402823466e+38f;
  float dx, dy, dz, d;
  dx = q0x - q1x; dy = q0y - q1y; dz = q0z - q1z; d = sqrtf((dx*dx + dy*dy) + dz*dz); m = fminf(m, d);
  dx = q0x - q2x; dy = q0y - q2y; dz = q0z - q2z; d = sqrtf((dx*dx + dy*dy) + dz*dz); m = fminf(m, d);
  dx = q0x - q3x; dy = q0y - q3y; dz = q0z - q3z; d = sqrtf((dx*dx + dy*dy) + dz*dz); m = fminf(m, d);
  dx = q1x - q2x; dy = q1y - q2y; dz = q1z - q2z; d = sqrtf((dx*dx + dy*dy) + dz*dz); m = fminf(m, d);
  dx = q1x - q3x; dy = q1y - q3y; dz = q1z - q3z; d = sqrtf((dx*dx + dy*dy) + dz*dz); m = fminf(m, d);
  dx = q2x - q3x; dy = q2y - q3y; dz = q2z - q3z; d = sqrtf((dx*dx + dy*dy) + dz*dz); m = fminf(m, d);
  return m;
}

// K1: setup [0,235) | new-geometry [235,470)
// (prio is now a direct global atomicMax from the setup range — verified
// correct in the round-1 fused run; the old 960-block slice/fold
// machinery and its 1.92MB pprio buffer are deleted.)
__global__ __launch_bounds__(256) void k_front(P p){
  int bb = blockIdx.x;
  if (bb < NB_SETUP){
    int t = bb * 256 + threadIdx.x;
    if (bb == 0){
      for (int j = threadIdx.x; j < 384; j += 256) p.counters[j] = 0;
    }
    if (t >= TOLD) return;
    int is64 = detect64(p.rawOld);
    int4 iv4 = load_tet4(p.rawOld, is64, t);
    int i0 = iv4.x, i1 = iv4.y, i2 = iv4.z, i3 = iv4.w;
    ((int4*)p.idxOld)[t] = iv4;

    // direct vertex-prio atomics (prio init -1 via 0xFF; contributions >= 0)
    atomicMax(&p.prio[i0], 0 * TOLD + t);
    atomicMax(&p.prio[i1], 1 * TOLD + t);
    atomicMax(&p.prio[i2], 2 * TOLD + t);
    atomicMax(&p.prio[i3], 3 * TOLD + t);

    // tet key insert; CAS winner plain-stores value, dup-key path (P~5e-8)
    // uses atomicMax. tvals poison (negative) always loses the max.
    {
      int s0 = i0, s1 = i1, s2 = i2, s3 = i3;
      cswap(s0, s1); cswap(s2, s3); cswap(s0, s2); cswap(s1, s3); cswap(s1, s2);
      unsigned long long key =
          (unsigned long long)((((long long)s0 * NVERT + s1) * NVERT + s2) * NVERT + s3);
      unsigned slot = hash64(key) & (THSZ - 1);
      while (true){
        unsigned long long prev = atomicCAS(&p.tkeys[slot], EMPTY64, key);
        if (prev == EMPTY64){ p.tvals[slot] = t; break; }
        if (prev == key){ atomicMax(&p.tvals[slot], t); break; }
        slot = (slot + 1) & (THSZ - 1);
      }
    }

    // 64-bit keyed DM face writes (racy last-wins; resolved in k_mid)
    if (p.dmMask){
      const int FO[4][3] = {{1, 2, 3}, {0, 2, 3}, {0, 1, 3}, {0, 1, 2}};
      int iv[4] = {i0, i1, i2, i3};
      #pragma unroll
      for (int l = 0; l < 4; ++l){
        int a = iv[FO[l][0]], b = iv[FO[l][1]], c = iv[FO[l][2]];
        cswap(a, b); cswap(a, c); cswap(b, c);
        unsigned long long fk = (unsigned long long)(((long long)a * NVERT + b) * NVERT + c);
        p.dm[hash64(fk) & p.dmMask] = (fk << 18) | (unsigned long long)(t * 4 + l);
      }
    }

    float q0x = p.verts[i0 * 3 + 0], q0y = p.verts[i0 * 3 + 1], q0z = p.verts[i0 * 3 + 2];
    float q1x = p.verts[i1 * 3 + 0], q1y = p.verts[i1 * 3 + 1], q1z = p.verts[i1 * 3 + 2];
    float q2x = p.verts[i2 * 3 + 0], q2y = p.verts[i2 * 3 + 1], q2z = p.verts[i2 * 3 + 2];
    float q3x = p.verts[i3 * 3 + 0], q3y = p.verts[i3 * 3 + 1], q3z = p.verts[i3 * 3 + 2];
    float e1x = q1x - q0x, e1y = q1y - q0y, e1z = q1z - q0z;
    float e2x = q2x - q0x, e2y = q2y - q0y, e2z = q2z - q0z;
    float e3x = q3x - q0x, e3y = q3y - q0y, e3z = q3z - q0z;
    float c23x = e2y * e3z - e2z * e3y;
    float c23y = e2z * e3x - e2x * e3z;
    float c23z = e2x * e3y - e2y * e3x;
    float det = e1x * c23x + e1y * c23y + e1z * c23z;
    int dg = (fabsf(det) < 1e-10f) ? 1 : 0;
    p.degen[t] = dg;
    float4 r0, r1, r2;
    if (dg){
      r0 = make_float4(1.f, 0.f, 0.f, q0x);
      r1 = make_float4(0.f, 1.f, 0.f, q0y);
      r2 = make_float4(0.f, 0.f, 1.f, q0z);
    } else {
      float inv = 1.0f / det;
      float c31x = e3y * e1z - e3z * e1y;
      float c31y = e3z * e1x - e3x * e1z;
      float c31z = e3x * e1y - e3y * e1x;
      float c12x = e1y * e2z - e1z * e2y;
      float c12y = e1z * e2x - e1x * e2z;
      float c12z = e1x * e2y - e1y * e2x;
      r0 = make_float4(c23x * inv, c23y * inv, c23z * inv, q0x);
      r1 = make_float4(c31x * inv, c31y * inv, c31z * inv, q0y);
      r2 = make_float4(c12x * inv, c12y * inv, c12z * inv, q0z);
    }
    p.Tv4[t * 3 + 0] = r0;
    p.Tv4[t * 3 + 1] = r1;
    p.Tv4[t * 3 + 2] = r2;
    float el = min_edge_r(q0x, q0y, q0z, q1x, q1y, q1z, q2x, q2y, q2z, q3x, q3y, q3z);
    p.cold4[t] = make_float4((((q0x + q1x) + q2x) + q3x) * 0.25f,
                             (((q0y + q1y) + q2y) + q3y) * 0.25f,
                             (((q0z + q1z) + q2z) + q3z) * 0.25f, el);
  } else {
    int n = (bb - NB_SETUP) * 256 + threadIdx.x;
    if (n >= TNEW) return;
    int is64 = detect64(p.rawNew);
    int4 ni = load_tet4(p.rawNew, is64, n);
    float q0x = p.verts[ni.x * 3 + 0], q0y = p.verts[ni.x * 3 + 1], q0z = p.verts[ni.x * 3 + 2];
    float q1x = p.verts[ni.y * 3 + 0], q1y = p.verts[ni.y * 3 + 1], q1z = p.verts[ni.y * 3 + 2];
    float q2x = p.verts[ni.z * 3 + 0], q2y = p.verts[ni.z * 3 + 1], q2z = p.verts[ni.z * 3 + 2];
    float q3x = p.verts[ni.w * 3 + 0], q3y = p.verts[ni.w * 3 + 1], q3z = p.verts[ni.w * 3 + 2];
    float el = min_edge_r(q0x, q0y, q0z, q1x, q1y, q1z, q2x, q2y, q2z, q3x, q3y, q3z);
    p.cnew4[n] = make_float4((((q0x + q1x) + q2x) + q3x) * 0.25f,
                             (((q0y + q1y) + q2y) + q3y) * 0.25f,
                             (((q0z + q1z) + q2z) + q3z) * 0.25f, el);
  }
}

// K2: face resolve [0,938) + new-tet match probe [938,1173)
__global__ __launch_bounds__(256) void k_mid(P p){
  int bb = blockIdx.x;
  if (bb < NB_FACE){
    int i = bb * 256 + threadIdx.x;
    if (i >= TOLD * 4) return;
    int t = i >> 2, l = i & 3;
    int4 iv4 = ((const int4*)p.idxOld)[t];
    int iv[4] = {iv4.x, iv4.y, iv4.z, iv4.w};
    const int FO[4][3] = {{1, 2, 3}, {0, 2, 3}, {0, 1, 3}, {0, 1, 2}};
    int a = iv[FO[l][0]], b = iv[FO[l][1]], c = iv[FO[l][2]];
    cswap(a, b); cswap(a, c); cswap(b, c);
    unsigned long long fk = (unsigned long long)(((long long)a * NVERT + b) * NVERT + c);
    if (p.dmMask){
      unsigned long long mine = (fk << 18) | (unsigned long long)i;
      unsigned long long got = p.dm[hash64(fk) & p.dmMask];
      if (got == mine) return;                       // self-winner; partner links both
      if ((got >> 18) == fk){                        // key-verified partner
        int wid = (int)(got & 0x3FFFFULL);
        p.nbr[i] = wid >> 2;
        p.nbr[wid] = t;
        return;
      }
    }
    face_insert(p.ftab, p.nbr, fk, t, l);            // bucket collision: exact CAS
  } else {
    int n = (bb - NB_FACE) * 256 + threadIdx.x;
    if (n >= TNEW) return;
    int is64 = detect64(p.rawNew);
    int4 ni = load_tet4(p.rawNew, is64, n);
    int s0 = ni.x, s1 = ni.y, s2 = ni.z, s3 = ni.w;
    cswap(s0, s1); cswap(s2, s3); cswap(s0, s2); cswap(s1, s3); cswap(s1, s2);
    unsigned long long key =
        (unsigned long long)((((long long)s0 * NVERT + s1) * NVERT + s2) * NVERT + s3);
    int m = -1;
    unsigned slot = hash64(key) & (THSZ - 1);
    while (true){
      unsigned long long k = p.tkeys[slot];
      if (k == EMPTY64) break;
      if (k == key){ m = p.tvals[slot]; break; }
      slot = (slot + 1) & (THSZ - 1);
    }
    p.matched[n] = m;
  }
}

// Per-walker output assembly. Fast path when all 5 candidates coincide.
__device__ __forceinline__ void assemble_walker(const P& p, int n, int m, int remap){
  int cds[5];
  if (m >= 0){
    cds[0] = cds[1] = cds[2] = cds[3] = cds[4] = m;
  } else {
    cds[0] = remap;
    int dg = p.degen[remap];
    int4 nb4 = ((const int4*)p.nbr)[remap];
    int nbl[4] = {nb4.x, nb4.y, nb4.z, nb4.w};
    for (int l = 0; l < 4; ++l){
      int fb = dg ? -1 : nbl[l];
      cds[1 + l] = (fb >= 0) ? fb : remap;
    }
  }
  bool same = (cds[1] == cds[0]) & (cds[2] == cds[0]) &
              (cds[3] == cds[0]) & (cds[4] == cds[0]);
  int is64 = detect64(p.rawNew);
  int4 ni = load_tet4(p.rawNew, is64, n);
  float nc0 = p.ncc[n * 3 + 0], nc1 = p.ncc[n * 3 + 1], nc2 = p.ncc[n * 3 + 2];
  float nelv = fmaxf(p.cnew4[n].w, 1e-8f);
  if (same){
    int ct = cds[0];
    int4 cv = ((const int4*)p.idxOld)[ct];
    int ov = 0;
    ov += (cv.x == ni.x || cv.x == ni.y || cv.x == ni.z || cv.x == ni.w) ? 1 : 0;
    ov += (cv.y == ni.x || cv.y == ni.y || cv.y == ni.z || cv.y == ni.w) ? 1 : 0;
    ov += (cv.z == ni.x || cv.z == ni.y || cv.z == ni.z || cv.z == ni.w) ? 1 : 0;
    ov += (cv.w == ni.x || cv.w == ni.y || cv.w == ni.z || cv.w == ni.w) ? 1 : 0;
    float d0 = p.occ[ct * 3 + 0] - nc0;
    float d1 = p.occ[ct * 3 + 1] - nc1;
    float d2 = p.occ[ct * 3 + 2] - nc2;
    float ccd2 = (d0 * d0 + d1 * d1) + d2 * d2;
    float raw = expf((float)ov * 2.0f) / (ccd2 + 1e-8f);
    float rsum = 0.0f;
    rsum += raw; rsum += raw; rsum += raw; rsum += raw; rsum += raw;
    float wgt = raw / rsum;
    float ds = p.cold4[ct].w / nelv;
    ds = fminf(fmaxf(ds, 0.1f), 10.0f);
    float cf = (float)ct;
    for (int c = 0; c < 5; ++c){
      p.out[n * 5 + c] = cf;
      p.out[TNEW * 5 + n * 5 + c] = wgt;
      p.out[2 * TNEW * 5 + n * 5 + c] = ds;
    }
    return;
  }
  float raws[5]; float rsum = 0.0f;
  float oels[5];
  for (int c = 0; c < 5; ++c){
    int ct = cds[c];
    int4 cv = ((const int4*)p.idxOld)[ct];
    int ov = 0;
    ov += (cv.x == ni.x || cv.x == ni.y || cv.x == ni.z || cv.x == ni.w) ? 1 : 0;
    ov += (cv.y == ni.x || cv.y == ni.y || cv.y == ni.z || cv.y == ni.w) ? 1 : 0;
    ov += (cv.z == ni.x || cv.z == ni.y || cv.z == ni.z || cv.z == ni.w) ? 1 : 0;
    ov += (cv.w == ni.x || cv.w == ni.y || cv.w == ni.z || cv.w == ni.w) ? 1 : 0;
    float d0 = p.occ[ct * 3 + 0] - nc0;
    float d1 = p.occ[ct * 3 + 1] - nc1;
    float d2 = p.occ[ct * 3 + 2] - nc2;
    float ccd2 = (d0 * d0 + d1 * d1) + d2 * d2;
    float raw = expf((float)ov * 2.0f) / (ccd2 + 1e-8f);
    raws[c] = raw; rsum += raw;
    oels[c] = p.cold4[ct].w;
  }
  for (int c = 0; c < 5; ++c){
    p.out[n * 5 + c] = (float)cds[c];
    p.out[TNEW * 5 + n * 5 + c] = raws[c] / rsum;
    float ds = oels[c] / nelv;
    ds = fminf(fmaxf(ds, 0.1f), 10.0f);
    p.out[2 * TNEW * 5 + n * 5 + c] = ds;
  }
}

// K3: per-walker local walk + LDS histogram + SPECULATIVE full assembly.
// A walker's output depends on the global stop-step S only via the partition
// settled(s<=S) vs fallback(s>S); we assemble as-if settled here (matched
// walkers have no S dependence at all), and K4 repairs the (normally empty)
// fallback set by overwriting those rows. Kernel-boundary ordering makes the
// overwrite race-free.
__global__ __launch_bounds__(256) void k_walkall(P p){
  __shared__ int s_hist[MAXSTEPS + 2];               // bins 0..301
  __shared__ int s_nw;
  for (int j = threadIdx.x; j < MAXSTEPS + 2; j += 256) s_hist[j] = 0;
  if (threadIdx.x == 0) s_nw = 0;
  __syncthreads();
  int n = blockIdx.x * blockDim.x + threadIdx.x;
  if (n < TNEW){
    int m = p.matched[n];
    if (m >= 0){
      assemble_walker(p, n, m, 0);                   // exact; S-independent
    } else {
      atomicAdd(&s_nw, 1);                           // LDS
      int is64 = detect64(p.rawNew);
      int i0 = is64 ? (int)((const long long*)p.rawNew)[n * 4] : ((const int*)p.rawNew)[n * 4];
      int pr = p.prio[i0];
      int c = (pr >= 0) ? (pr % TOLD) : 0;           // seed
      float4 cn = p.cnew4[n];
      int s = MAXSTEPS + 1;                          // 301 = never settles
      for (int k = 1; k <= MAXSTEPS; ++k){
        float4 r0 = p.Tv4[c * 3 + 0];
        float4 r1 = p.Tv4[c * 3 + 1];
        float4 r2 = p.Tv4[c * 3 + 2];
        float rx = cn.x - r0.w, ry = cn.y - r1.w, rz = cn.z - r2.w;
        float b0 = r0.x * rx + r0.y * ry + r0.z * rz;
        float b1 = r1.x * rx + r1.y * ry + r1.z * rz;
        float b2 = r2.x * rx + r2.y * ry + r2.z * rz;
        float a0 = 1.0f - (b0 + b1 + b2);
        float ab[4] = {a0, b0, b1, b2};
        int amin = 0; float mn = ab[0];
        for (int j = 1; j < 4; ++j){ if (ab[j] < mn){ mn = ab[j]; amin = j; } }
        if (mn >= -0.0001f){ s = k; break; }                    // converged
        int nb = p.degen[c] ? -1 : p.nbr[c * 4 + amin];
        if (nb < 0){ s = k; break; }                            // boundary
        c = nb;
      }
      p.sstep[n] = s;
      atomicAdd(&s_hist[s], 1);                      // LDS
      assemble_walker(p, n, -1, c);                  // speculative (settled c)
    }
  }
  __syncthreads();
  if (threadIdx.x == 0 && s_nw) atomicAdd(&p.counters[0], s_nw);
  for (int j = threadIdx.x; j < MAXSTEPS + 2; j += 256){
    int v = s_hist[j];
    if (v) atomicAdd(&p.counters[64 + j], v);        // ~1-2 nonzero bins/block
  }
}

// Exact loop-exit step from the settle-step histogram:
// count_k = nw - sum_{j<=k} hist[j]; S = first k in [0,300] with count_k < thr
// (thr = max(100, nw/1000)), else 300 (MAXSTEPS bound).
__device__ __forceinline__ int compute_S(const int* counters){
  int nw = counters[0];
  int thr = max(100, nw / 1000);
  if (nw < thr) return 0;
  int cnt = nw;
  for (int k = 1; k <= MAXSTEPS; ++k){
    cnt -= counters[64 + k];
    if (cnt < thr) return k;
  }
  return MAXSTEPS;
}

// K4: repair pass only. Each block derives S, scans its 500-walker slice for
// fallback-owned walkers (matched<0 && sstep>S; normally zero), and for hits
// runs the cooperative nearest-centroid fallback + re-assembly, overwriting
// the speculative rows from K3.
__global__ __launch_bounds__(256) void k_tail(P p){
  __shared__ float sd[256];
  __shared__ int si[256];
  __shared__ int s_hits[256];
  __shared__ int s_nhits;
  __shared__ int s_S;
  if (threadIdx.x == 0) s_S = compute_S(p.counters);
  __syncthreads();
  int S = s_S;
  int base = blockIdx.x * FBRANGE;
  for (int chunk = base; chunk < base + FBRANGE; chunk += 256){
    if (threadIdx.x == 0) s_nhits = 0;
    __syncthreads();
    int n = chunk + threadIdx.x;
    if (n < base + FBRANGE && n < TNEW){
      if (p.matched[n] < 0 && p.sstep[n] > S)
        s_hits[atomicAdd(&s_nhits, 1)] = n;
    }
    __syncthreads();
    int nh = s_nhits;
    for (int h = 0; h < nh; ++h){
      int n2 = s_hits[h];
      float4 cn = p.cnew4[n2];
      float cx = cn.x, cy = cn.y, cz = cn.z;
      float p2 = (cx * cx + cy * cy) + cz * cz;
      float bd = 3.402823466e+38f; int bi = 0;
      for (int j = threadIdx.x; j < TOLD; j += 256){
        float4 oc = p.cold4[j];
        float dot = (cx * oc.x + cy * oc.y) + cz * oc.z;
        float c2 = (oc.x * oc.x + oc.y * oc.y) + oc.z * oc.z;
        float d = (p2 - 2.0f * dot) + c2;
        if (d < bd || (d == bd && j < bi)){ bd = d; bi = j; }
      }
      sd[threadIdx.x] = bd; si[threadIdx.x] = bi;
      __syncthreads();
      for (int s = 128; s > 0; s >>= 1){
        if ((int)threadIdx.x < s){
          float od = sd[threadIdx.x + s]; int oi = si[threadIdx.x + s];
          if (od < sd[threadIdx.x] || (od == sd[threadIdx.x] && oi < si[threadIdx.x])){
            sd[threadIdx.x] = od; si[threadIdx.x] = oi;
          }
        }
        __syncthreads();
      }
      if (threadIdx.x == 0){
        int r = si[0];
        if (r < 0) r = 0; if (r > TOLD - 1) r = TOLD - 1;
        assemble_walker(p, n2, -1, r);
      }
      __syncthreads();
    }
    __syncthreads();
  }
}

extern "C" void kernel_launch(void* const* d_in, const int* in_sizes, int n_in,
                              void* d_out, int out_size, void* d_ws, size_t ws_size,
                              hipStream_t stream) {
  char* w = (char*)d_ws;
  P p;
  p.rawNew = (const unsigned int*)d_in[0];
  p.rawOld = (const unsigned int*)d_in[1];
  p.occ    = (const float*)d_in[2];
  p.ncc    = (const float*)d_in[3];
  p.verts  = (const float*)d_in[4];
  p.out    = (float*)d_out;
  p.tkeys    = (unsigned long long*)(w + OFF_TKEYS);
  p.ftab     = (unsigned long long*)(w + OFF_FTAB);
  p.nbr      = (int*)(w + OFF_NBR);
  p.prio     = (int*)(w + OFF_PRIO);
  p.counters = (int*)(w + OFF_CNT);
  p.tvals    = (int*)(w + OFF_TVALS);
  p.idxOld   = (int*)(w + OFF_IDXOLD);
  p.sstep    = (int*)(w + OFF_SSTEP);
  p.degen    = (int*)(w + OFF_DEGEN);
  p.matched  = (int*)(w + OFF_MATCHED);
  p.Tv4      = (float4*)(w + OFF_TV4);
  p.cold4    = (float4*)(w + OFF_COLD4);
  p.cnew4    = (float4*)(w + OFF_CNEW4);
  p.dm       = (unsigned long long*)(w + OFF_DM);
  size_t avail = (ws_size > (size_t)OFF_DM) ? ws_size - (size_t)OFF_DM : 0;
  unsigned dmMask = 0;
  for (int bshift = 21; bshift >= 16; --bshift){
    if (avail >= ((size_t)8 << bshift)){ dmMask = (1u << bshift) - 1u; break; }
  }
  p.dmMask = dmMask;

  hipMemsetAsync(w, 0xFF, FF_BYTES, stream);
  hipLaunchKernelGGL(k_front,   dim3(NB_SETUP + NB_NEWG), dim3(256), 0, stream, p);
  hipLaunchKernelGGL(k_mid,     dim3(NB_FACE + NB_MATCH), dim3(256), 0, stream, p);
  hipLaunchKernelGGL(k_walkall, dim3((TNEW + 255) / 256), dim3(256), 0, stream, p);
  hipLaunchKernelGGL(k_tail,    dim3(NB_FB), dim3(256), 0, stream, p);
}

// Round 4
// 115.849 us; speedup vs baseline: 3.6684x; 1.0058x over previous
//
#include <hip/hip_runtime.h>

#pragma clang fp contract(off)

#define TOLD 60000
#define TNEW 60000
#define NVERT 30000
#define MAXSTEPS 300
#define THSZ 131072                  // tet-key hash slots (exact, CAS)
#define FHSZ 131072                  // exact CAS face table (DM-collision fallback only)
#define EMPTY64 0xFFFFFFFFFFFFFFFFULL

// K1 block-range split: setup | new-geometry | FF-region init
#define NB_SETUP 235                 // ceil(60000/256)
#define NB_NEWG  235
#define NB_INIT  194                 // ceil(198572 uint4 / 1024 per block)
// K2: face resolve only (tet insert + prio ride along on l==0 lanes)
#define NB_FACE  938                 // ceil(240000/256)
// K3: walkers
#define NB_WALK  235
// K4: repair-only pass
#define NB_FB    120                 // fallback blocks (scan 500 walkers each)
#define FBRANGE  (TNEW / NB_FB)      // 500

// workspace layout: [0xFF-init region][rest, no init needed]
#define OFF_TKEYS    0u              // 131072*8 = 1,048,576
#define OFF_FTAB     1048576u        // 131072*8 = 1,048,576
#define OFF_NBR      2097152u        // 240000*4 =   960,000
#define OFF_PRIO     3057152u        // 30000*4  =   120,000 (0xFF = -1; atomicMax target)
#define FF_BYTES     3177152u        // end of 0xFF region (= 198,572 uint4)
#define FF_UINT4     198572u
#define OFF_CNT      3177152u        // 2048 B: counters[0..63] + hist[64..365] (zeroed by K1 blk0)
#define OFF_TVALS    3179200u        // 524,288 (poison-safe)
#define OFF_IDXOLD   3703552u        // 960,000 (16B aligned)
#define OFF_SSTEP    4663552u        // 240,000 (0 for matched; settle step otherwise)
#define OFF_DEGEN    4903552u        // 240,000
#define OFF_TV4      5383552u        // 2,880,000 (3 float4/tet: Tinv row + v0 comp)
#define OFF_COLD4    8263552u        // 960,000 (centroid, oel)
#define OFF_CNEW4    9223552u        // 960,000 (centroid, nel)
#define OFF_DM       10183552u       // 64-bit keyed DM face table (uninit/poison-safe)

struct P {
  const unsigned int* rawNew;
  const unsigned int* rawOld;
  const float* occ;
  const float* ncc;
  const float* verts;
  float* out;
  unsigned long long* tkeys;
  unsigned long long* ftab;
  int* counters;   // [0]=n_walk; [64..365]=hist[s] (settle-step histogram)
  int* tvals;
  int* idxOld;
  int* nbr;
  int* prio;       // direct atomicMax target, init -1 via K1 FF-init
  int* sstep;
  int* degen;
  float4* Tv4;
  float4* cold4;
  float4* cnew4;
  unsigned long long* dm;            // (key<<18 | tet*4+local), racy last-wins
  unsigned int dmMask;
};

__device__ __forceinline__ unsigned hash64(unsigned long long k){
  k ^= k >> 33; k *= 0xff51afd7ed558ccdULL;
  k ^= k >> 33; k *= 0xc4ceb9fe1a85ec53ULL;
  k ^= k >> 33;
  return (unsigned)k;
}
__device__ __forceinline__ void cswap(int& a, int& b){ if (a > b){ int t = a; a = b; b = t; } }

__device__ __forceinline__ int detect64(const unsigned int* raw){
  unsigned acc = 0;
  const uint4* r4 = (const uint4*)raw;
  #pragma unroll
  for (int k = 0; k < 32; ++k){ uint4 v = r4[k]; acc |= (v.y | v.w); }
  return acc == 0u;
}

__device__ __forceinline__ int4 load_tet4(const unsigned int* raw, int is64, int t){
  if (is64){
    uint4 a = ((const uint4*)raw)[t * 2 + 0];
    uint4 b = ((const uint4*)raw)[t * 2 + 1];
    return make_int4((int)a.x, (int)a.z, (int)b.x, (int)b.z);
  }
  uint4 a = ((const uint4*)raw)[t];
  return make_int4((int)a.x, (int)a.y, (int)a.z, (int)a.w);
}

__device__ __forceinline__ void face_insert(unsigned long long* ftab, int* nbr,
                                            unsigned long long fkey, int t, int l){
  unsigned long long mine = (fkey << 18) | (unsigned long long)(t * 4 + l);
  unsigned slot = hash64(fkey ^ 0x9e3779b97f4a7c15ULL) & (FHSZ - 1);
  while (true){
    unsigned long long prev = atomicCAS(&ftab[slot], EMPTY64, mine);
    if (prev == EMPTY64) return;
    if ((prev >> 18) == fkey){
      int oid = (int)(prev & 0x3FFFFULL);
      nbr[t * 4 + l] = oid >> 2;
      nbr[oid] = t;
      return;
    }
    slot = (slot + 1) & (FHSZ - 1);
  }
}

__device__ __forceinline__ float min_edge_r(
    float q0x, float q0y, float q0z, float q1x, float q1y, float q1z,
    float q2x, float q2y, float q2z, float q3x, float q3y, float q3z){
  float m = 3.402823466e+38f;
  float dx, dy, dz, d;
  dx = q0x - q1x; dy = q0y - q1y; dz = q0z - q1z; d = sqrtf((dx*dx + dy*dy) + dz*dz); m = fminf(m, d);
  dx = q0x - q2x; dy = q0y - q2y; dz = q0z - q2z; d = sqrtf((dx*dx + dy*dy) + dz*dz); m = fminf(m, d);
  dx = q0x - q3x; dy = q0y - q3y; dz = q0z - q3z; d = sqrtf((dx*dx + dy*dy) + dz*dz); m = fminf(m, d);
  dx = q1x - q2x; dy = q1y - q2y; dz = q1z - q2z; d = sqrtf((dx*dx + dy*dy) + dz*dz); m = fminf(m, d);
  dx = q1x - q3x; dy = q1y - q3y; dz = q1z - q3z; d = sqrtf((dx*dx + dy*dy) + dz*dz); m = fminf(m, d);
  dx = q2x - q3x; dy = q2y - q3y; dz = q2z - q3z; d = sqrtf((dx*dx + dy*dy) + dz*dz); m = fminf(m, d);
  return m;
}

// K1: setup [0,235) | new-geometry [235,470) | FF-region init [470,664).
// Setup no longer touches any FF-initialized table (tet insert + prio moved
// to K2), so the init blocks can run concurrently; the K1->K2 kernel
// boundary orders init before first use. This deletes the hipMemsetAsync
// dispatch entirely.
__global__ __launch_bounds__(256) void k_front(P p){
  int bb = blockIdx.x;
  if (bb < NB_SETUP){
    if (bb == 0){
      for (int j = threadIdx.x; j < 384; j += 256) p.counters[j] = 0;
    }
    int t = bb * 256 + threadIdx.x;
    if (t >= TOLD) return;
    int is64 = detect64(p.rawOld);
    int4 iv4 = load_tet4(p.rawOld, is64, t);
    int i0 = iv4.x, i1 = iv4.y, i2 = iv4.z, i3 = iv4.w;
    ((int4*)p.idxOld)[t] = iv4;

    // 64-bit keyed DM face writes (racy last-wins; resolved in K2).
    // Every slot K2 reads was written here (same fk -> same slot), so no
    // init is required for dm.
    if (p.dmMask){
      const int FO[4][3] = {{1, 2, 3}, {0, 2, 3}, {0, 1, 3}, {0, 1, 2}};
      int iv[4] = {i0, i1, i2, i3};
      #pragma unroll
      for (int l = 0; l < 4; ++l){
        int a = iv[FO[l][0]], b = iv[FO[l][1]], c = iv[FO[l][2]];
        cswap(a, b); cswap(a, c); cswap(b, c);
        unsigned long long fk = (unsigned long long)(((long long)a * NVERT + b) * NVERT + c);
        p.dm[hash64(fk) & p.dmMask] = (fk << 18) | (unsigned long long)(t * 4 + l);
      }
    }

    float q0x = p.verts[i0 * 3 + 0], q0y = p.verts[i0 * 3 + 1], q0z = p.verts[i0 * 3 + 2];
    float q1x = p.verts[i1 * 3 + 0], q1y = p.verts[i1 * 3 + 1], q1z = p.verts[i1 * 3 + 2];
    float q2x = p.verts[i2 * 3 + 0], q2y = p.verts[i2 * 3 + 1], q2z = p.verts[i2 * 3 + 2];
    float q3x = p.verts[i3 * 3 + 0], q3y = p.verts[i3 * 3 + 1], q3z = p.verts[i3 * 3 + 2];
    float e1x = q1x - q0x, e1y = q1y - q0y, e1z = q1z - q0z;
    float e2x = q2x - q0x, e2y = q2y - q0y, e2z = q2z - q0z;
    float e3x = q3x - q0x, e3y = q3y - q0y, e3z = q3z - q0z;
    float c23x = e2y * e3z - e2z * e3y;
    float c23y = e2z * e3x - e2x * e3z;
    float c23z = e2x * e3y - e2y * e3x;
    float det = e1x * c23x + e1y * c23y + e1z * c23z;
    int dg = (fabsf(det) < 1e-10f) ? 1 : 0;
    p.degen[t] = dg;
    float4 r0, r1, r2;
    if (dg){
      r0 = make_float4(1.f, 0.f, 0.f, q0x);
      r1 = make_float4(0.f, 1.f, 0.f, q0y);
      r2 = make_float4(0.f, 0.f, 1.f, q0z);
    } else {
      float inv = 1.0f / det;
      float c31x = e3y * e1z - e3z * e1y;
      float c31y = e3z * e1x - e3x * e1z;
      float c31z = e3x * e1y - e3y * e1x;
      float c12x = e1y * e2z - e1z * e2y;
      float c12y = e1z * e2x - e1x * e2z;
      float c12z = e1x * e2y - e1y * e2x;
      r0 = make_float4(c23x * inv, c23y * inv, c23z * inv, q0x);
      r1 = make_float4(c31x * inv, c31y * inv, c31z * inv, q0y);
      r2 = make_float4(c12x * inv, c12y * inv, c12z * inv, q0z);
    }
    p.Tv4[t * 3 + 0] = r0;
    p.Tv4[t * 3 + 1] = r1;
    p.Tv4[t * 3 + 2] = r2;
    float el = min_edge_r(q0x, q0y, q0z, q1x, q1y, q1z, q2x, q2y, q2z, q3x, q3y, q3z);
    p.cold4[t] = make_float4((((q0x + q1x) + q2x) + q3x) * 0.25f,
                             (((q0y + q1y) + q2y) + q3y) * 0.25f,
                             (((q0z + q1z) + q2z) + q3z) * 0.25f, el);
  } else if (bb < NB_SETUP + NB_NEWG){
    int n = (bb - NB_SETUP) * 256 + threadIdx.x;
    if (n >= TNEW) return;
    int is64 = detect64(p.rawNew);
    int4 ni = load_tet4(p.rawNew, is64, n);
    float q0x = p.verts[ni.x * 3 + 0], q0y = p.verts[ni.x * 3 + 1], q0z = p.verts[ni.x * 3 + 2];
    float q1x = p.verts[ni.y * 3 + 0], q1y = p.verts[ni.y * 3 + 1], q1z = p.verts[ni.y * 3 + 2];
    float q2x = p.verts[ni.z * 3 + 0], q2y = p.verts[ni.z * 3 + 1], q2z = p.verts[ni.z * 3 + 2];
    float q3x = p.verts[ni.w * 3 + 0], q3y = p.verts[ni.w * 3 + 1], q3z = p.verts[ni.w * 3 + 2];
    float el = min_edge_r(q0x, q0y, q0z, q1x, q1y, q1z, q2x, q2y, q2z, q3x, q3y, q3z);
    p.cnew4[n] = make_float4((((q0x + q1x) + q2x) + q3x) * 0.25f,
                             (((q0y + q1y) + q2y) + q3y) * 0.25f,
                             (((q0z + q1z) + q2z) + q3z) * 0.25f, el);
  } else {
    // FF-init of tkeys|ftab|nbr|prio (contiguous from workspace offset 0)
    unsigned idx = (unsigned)(bb - NB_SETUP - NB_NEWG) * 1024u + threadIdx.x * 4u;
    uint4 ff = make_uint4(~0u, ~0u, ~0u, ~0u);
    uint4* base = (uint4*)p.tkeys;
    #pragma unroll
    for (unsigned k = 0; k < 4; ++k){
      unsigned id = idx + k;
      if (id < FF_UINT4) base[id] = ff;
    }
  }
}

// K2: face resolve (all 240K face-slots); l==0 lanes additionally do the
// tet-key CAS insert + vertex-prio atomicMax (tables FF-init'd in K1;
// consumed in K3 -> K2 is early enough).
__global__ __launch_bounds__(256) void k_mid(P p){
  int i = blockIdx.x * 256 + threadIdx.x;
  if (i >= TOLD * 4) return;
  int t = i >> 2, l = i & 3;
  int4 iv4 = ((const int4*)p.idxOld)[t];
  int iv[4] = {iv4.x, iv4.y, iv4.z, iv4.w};

  if (l == 0){
    // direct vertex-prio atomics (prio init -1; contributions >= 0)
    atomicMax(&p.prio[iv4.x], 0 * TOLD + t);
    atomicMax(&p.prio[iv4.y], 1 * TOLD + t);
    atomicMax(&p.prio[iv4.z], 2 * TOLD + t);
    atomicMax(&p.prio[iv4.w], 3 * TOLD + t);
    // tet key insert; CAS winner plain-stores value, dup-key path (P~5e-8)
    // uses atomicMax. tvals poison (negative) always loses the max.
    int s0 = iv4.x, s1 = iv4.y, s2 = iv4.z, s3 = iv4.w;
    cswap(s0, s1); cswap(s2, s3); cswap(s0, s2); cswap(s1, s3); cswap(s1, s2);
    unsigned long long key =
        (unsigned long long)((((long long)s0 * NVERT + s1) * NVERT + s2) * NVERT + s3);
    unsigned slot = hash64(key) & (THSZ - 1);
    while (true){
      unsigned long long prev = atomicCAS(&p.tkeys[slot], EMPTY64, key);
      if (prev == EMPTY64){ p.tvals[slot] = t; break; }
      if (prev == key){ atomicMax(&p.tvals[slot], t); break; }
      slot = (slot + 1) & (THSZ - 1);
    }
  }

  const int FO[4][3] = {{1, 2, 3}, {0, 2, 3}, {0, 1, 3}, {0, 1, 2}};
  int a = iv[FO[l][0]], b = iv[FO[l][1]], c = iv[FO[l][2]];
  cswap(a, b); cswap(a, c); cswap(b, c);
  unsigned long long fk = (unsigned long long)(((long long)a * NVERT + b) * NVERT + c);
  if (p.dmMask){
    unsigned long long mine = (fk << 18) | (unsigned long long)i;
    unsigned long long got = p.dm[hash64(fk) & p.dmMask];
    if (got == mine) return;                       // self-winner; partner links both
    if ((got >> 18) == fk){                        // key-verified partner
      int wid = (int)(got & 0x3FFFFULL);
      p.nbr[i] = wid >> 2;
      p.nbr[wid] = t;
      return;
    }
  }
  face_insert(p.ftab, p.nbr, fk, t, l);            // bucket collision: exact CAS
}

// Per-walker output assembly. Fast path when all 5 candidates coincide.
// is64/ni are hoisted by the caller (single detect64 per thread).
__device__ __forceinline__ void assemble_walker(const P& p, int n, int m, int remap,
                                                int4 ni){
  int cds[5];
  if (m >= 0){
    cds[0] = cds[1] = cds[2] = cds[3] = cds[4] = m;
  } else {
    cds[0] = remap;
    int dg = p.degen[remap];
    int4 nb4 = ((const int4*)p.nbr)[remap];
    int nbl[4] = {nb4.x, nb4.y, nb4.z, nb4.w};
    for (int l = 0; l < 4; ++l){
      int fb = dg ? -1 : nbl[l];
      cds[1 + l] = (fb >= 0) ? fb : remap;
    }
  }
  bool same = (cds[1] == cds[0]) & (cds[2] == cds[0]) &
              (cds[3] == cds[0]) & (cds[4] == cds[0]);
  float nc0 = p.ncc[n * 3 + 0], nc1 = p.ncc[n * 3 + 1], nc2 = p.ncc[n * 3 + 2];
  float nelv = fmaxf(p.cnew4[n].w, 1e-8f);
  if (same){
    int ct = cds[0];
    int4 cv = ((const int4*)p.idxOld)[ct];
    int ov = 0;
    ov += (cv.x == ni.x || cv.x == ni.y || cv.x == ni.z || cv.x == ni.w) ? 1 : 0;
    ov += (cv.y == ni.x || cv.y == ni.y || cv.y == ni.z || cv.y == ni.w) ? 1 : 0;
    ov += (cv.z == ni.x || cv.z == ni.y || cv.z == ni.z || cv.z == ni.w) ? 1 : 0;
    ov += (cv.w == ni.x || cv.w == ni.y || cv.w == ni.z || cv.w == ni.w) ? 1 : 0;
    float d0 = p.occ[ct * 3 + 0] - nc0;
    float d1 = p.occ[ct * 3 + 1] - nc1;
    float d2 = p.occ[ct * 3 + 2] - nc2;
    float ccd2 = (d0 * d0 + d1 * d1) + d2 * d2;
    float raw = expf((float)ov * 2.0f) / (ccd2 + 1e-8f);
    float rsum = 0.0f;
    rsum += raw; rsum += raw; rsum += raw; rsum += raw; rsum += raw;
    float wgt = raw / rsum;
    float ds = p.cold4[ct].w / nelv;
    ds = fminf(fmaxf(ds, 0.1f), 10.0f);
    float cf = (float)ct;
    for (int c = 0; c < 5; ++c){
      p.out[n * 5 + c] = cf;
      p.out[TNEW * 5 + n * 5 + c] = wgt;
      p.out[2 * TNEW * 5 + n * 5 + c] = ds;
    }
    return;
  }
  float raws[5]; float rsum = 0.0f;
  float oels[5];
  for (int c = 0; c < 5; ++c){
    int ct = cds[c];
    int4 cv = ((const int4*)p.idxOld)[ct];
    int ov = 0;
    ov += (cv.x == ni.x || cv.x == ni.y || cv.x == ni.z || cv.x == ni.w) ? 1 : 0;
    ov += (cv.y == ni.x || cv.y == ni.y || cv.y == ni.z || cv.y == ni.w) ? 1 : 0;
    ov += (cv.z == ni.x || cv.z == ni.y || cv.z == ni.z || cv.z == ni.w) ? 1 : 0;
    ov += (cv.w == ni.x || cv.w == ni.y || cv.w == ni.z || cv.w == ni.w) ? 1 : 0;
    float d0 = p.occ[ct * 3 + 0] - nc0;
    float d1 = p.occ[ct * 3 + 1] - nc1;
    float d2 = p.occ[ct * 3 + 2] - nc2;
    float ccd2 = (d0 * d0 + d1 * d1) + d2 * d2;
    float raw = expf((float)ov * 2.0f) / (ccd2 + 1e-8f);
    raws[c] = raw; rsum += raw;
    oels[c] = p.cold4[ct].w;
  }
  for (int c = 0; c < 5; ++c){
    p.out[n * 5 + c] = (float)cds[c];
    p.out[TNEW * 5 + n * 5 + c] = raws[c] / rsum;
    float ds = oels[c] / nelv;
    ds = fminf(fmaxf(ds, 0.1f), 10.0f);
    p.out[2 * TNEW * 5 + n * 5 + c] = ds;
  }
}

// K3: inline tet-match probe + per-walker local walk + LDS histogram +
// SPECULATIVE full assembly. matched[] is gone: matched walkers record
// sstep=0 (never repaired since S>=0); unmatched record their settle step.
// K4 repairs the (normally empty) fallback set by overwriting rows.
__global__ __launch_bounds__(256) void k_walkall(P p){
  __shared__ int s_hist[MAXSTEPS + 2];               // bins 0..301
  __shared__ int s_nw;
  for (int j = threadIdx.x; j < MAXSTEPS + 2; j += 256) s_hist[j] = 0;
  if (threadIdx.x == 0) s_nw = 0;
  __syncthreads();
  int n = blockIdx.x * blockDim.x + threadIdx.x;
  if (n < TNEW){
    int is64 = detect64(p.rawNew);                   // single detect per thread
    int4 ni = load_tet4(p.rawNew, is64, n);
    // tet-match probe (tkeys/tvals complete after K2)
    int m = -1;
    {
      int s0 = ni.x, s1 = ni.y, s2 = ni.z, s3 = ni.w;
      cswap(s0, s1); cswap(s2, s3); cswap(s0, s2); cswap(s1, s3); cswap(s1, s2);
      unsigned long long key =
          (unsigned long long)((((long long)s0 * NVERT + s1) * NVERT + s2) * NVERT + s3);
      unsigned slot = hash64(key) & (THSZ - 1);
      while (true){
        unsigned long long k = p.tkeys[slot];
        if (k == EMPTY64) break;
        if (k == key){ m = p.tvals[slot]; break; }
        slot = (slot + 1) & (THSZ - 1);
      }
    }
    if (m >= 0){
      p.sstep[n] = 0;                                // never selected for repair
      assemble_walker(p, n, m, 0, ni);               // exact; S-independent
    } else {
      atomicAdd(&s_nw, 1);                           // LDS
      int pr = p.prio[ni.x];                         // i0 = first new vertex
      int c = (pr >= 0) ? (pr % TOLD) : 0;           // seed
      float4 cn = p.cnew4[n];
      int s = MAXSTEPS + 1;                          // 301 = never settles
      for (int k = 1; k <= MAXSTEPS; ++k){
        float4 r0 = p.Tv4[c * 3 + 0];
        float4 r1 = p.Tv4[c * 3 + 1];
        float4 r2 = p.Tv4[c * 3 + 2];
        float rx = cn.x - r0.w, ry = cn.y - r1.w, rz = cn.z - r2.w;
        float b0 = r0.x * rx + r0.y * ry + r0.z * rz;
        float b1 = r1.x * rx + r1.y * ry + r1.z * rz;
        float b2 = r2.x * rx + r2.y * ry + r2.z * rz;
        float a0 = 1.0f - (b0 + b1 + b2);
        float ab[4] = {a0, b0, b1, b2};
        int amin = 0; float mn = ab[0];
        for (int j = 1; j < 4; ++j){ if (ab[j] < mn){ mn = ab[j]; amin = j; } }
        if (mn >= -0.0001f){ s = k; break; }                    // converged
        int nb = p.degen[c] ? -1 : p.nbr[c * 4 + amin];
        if (nb < 0){ s = k; break; }                            // boundary
        c = nb;
      }
      p.sstep[n] = s;
      atomicAdd(&s_hist[s], 1);                      // LDS
      assemble_walker(p, n, -1, c, ni);              // speculative (settled c)
    }
  }
  __syncthreads();
  if (threadIdx.x == 0 && s_nw) atomicAdd(&p.counters[0], s_nw);
  for (int j = threadIdx.x; j < MAXSTEPS + 2; j += 256){
    int v = s_hist[j];
    if (v) atomicAdd(&p.counters[64 + j], v);        // ~1-2 nonzero bins/block
  }
}

// Exact loop-exit step from the settle-step histogram:
// count_k = nw - sum_{j<=k} hist[j]; S = first k in [0,300] with count_k < thr
// (thr = max(100, nw/1000)), else 300 (MAXSTEPS bound).
__device__ __forceinline__ int compute_S(const int* counters){
  int nw = counters[0];
  int thr = max(100, nw / 1000);
  if (nw < thr) return 0;
  int cnt = nw;
  for (int k = 1; k <= MAXSTEPS; ++k){
    cnt -= counters[64 + k];
    if (cnt < thr) return k;
  }
  return MAXSTEPS;
}

// K4: repair pass only. Each block derives S, scans its 500-walker slice for
// fallback-owned walkers (sstep>S; normally zero; matched have sstep=0), and
// for hits runs the cooperative nearest-centroid fallback + re-assembly,
// overwriting the speculative rows from K3.
__global__ __launch_bounds__(256) void k_tail(P p){
  __shared__ float sd[256];
  __shared__ int si[256];
  __shared__ int s_hits[256];
  __shared__ int s_nhits;
  __shared__ int s_S;
  if (threadIdx.x == 0) s_S = compute_S(p.counters);
  __syncthreads();
  int S = s_S;
  int base = blockIdx.x * FBRANGE;
  for (int chunk = base; chunk < base + FBRANGE; chunk += 256){
    if (threadIdx.x == 0) s_nhits = 0;
    __syncthreads();
    int n = chunk + threadIdx.x;
    if (n < base + FBRANGE && n < TNEW){
      if (p.sstep[n] > S)
        s_hits[atomicAdd(&s_nhits, 1)] = n;
    }
    __syncthreads();
    int nh = s_nhits;
    for (int h = 0; h < nh; ++h){
      int n2 = s_hits[h];
      float4 cn = p.cnew4[n2];
      float cx = cn.x, cy = cn.y, cz = cn.z;
      float p2 = (cx * cx + cy * cy) + cz * cz;
      float bd = 3.402823466e+38f; int bi = 0;
      for (int j = threadIdx.x; j < TOLD; j += 256){
        float4 oc = p.cold4[j];
        float dot = (cx * oc.x + cy * oc.y) + cz * oc.z;
        float c2 = (oc.x * oc.x + oc.y * oc.y) + oc.z * oc.z;
        float d = (p2 - 2.0f * dot) + c2;
        if (d < bd || (d == bd && j < bi)){ bd = d; bi = j; }
      }
      sd[threadIdx.x] = bd; si[threadIdx.x] = bi;
      __syncthreads();
      for (int s = 128; s > 0; s >>= 1){
        if ((int)threadIdx.x < s){
          float od = sd[threadIdx.x + s]; int oi = si[threadIdx.x + s];
          if (od < sd[threadIdx.x] || (od == sd[threadIdx.x] && oi < si[threadIdx.x])){
            sd[threadIdx.x] = od; si[threadIdx.x] = oi;
          }
        }
        __syncthreads();
      }
      if (threadIdx.x == 0){
        int r = si[0];
        if (r < 0) r = 0; if (r > TOLD - 1) r = TOLD - 1;
        int is64 = detect64(p.rawNew);
        int4 ni = load_tet4(p.rawNew, is64, n2);
        assemble_walker(p, n2, -1, r, ni);
      }
      __syncthreads();
    }
    __syncthreads();
  }
}

extern "C" void kernel_launch(void* const* d_in, const int* in_sizes, int n_in,
                              void* d_out, int out_size, void* d_ws, size_t ws_size,
                              hipStream_t stream) {
  char* w = (char*)d_ws;
  P p;
  p.rawNew = (const unsigned int*)d_in[0];
  p.rawOld = (const unsigned int*)d_in[1];
  p.occ    = (const float*)d_in[2];
  p.ncc    = (const float*)d_in[3];
  p.verts  = (const float*)d_in[4];
  p.out    = (float*)d_out;
  p.tkeys    = (unsigned long long*)(w + OFF_TKEYS);
  p.ftab     = (unsigned long long*)(w + OFF_FTAB);
  p.nbr      = (int*)(w + OFF_NBR);
  p.prio     = (int*)(w + OFF_PRIO);
  p.counters = (int*)(w + OFF_CNT);
  p.tvals    = (int*)(w + OFF_TVALS);
  p.idxOld   = (int*)(w + OFF_IDXOLD);
  p.sstep    = (int*)(w + OFF_SSTEP);
  p.degen    = (int*)(w + OFF_DEGEN);
  p.Tv4      = (float4*)(w + OFF_TV4);
  p.cold4    = (float4*)(w + OFF_COLD4);
  p.cnew4    = (float4*)(w + OFF_CNEW4);
  p.dm       = (unsigned long long*)(w + OFF_DM);
  size_t avail = (ws_size > (size_t)OFF_DM) ? ws_size - (size_t)OFF_DM : 0;
  unsigned dmMask = 0;
  for (int bshift = 21; bshift >= 16; --bshift){
    if (avail >= ((size_t)8 << bshift)){ dmMask = (1u << bshift) - 1u; break; }
  }
  p.dmMask = dmMask;

  hipLaunchKernelGGL(k_front,   dim3(NB_SETUP + NB_NEWG + NB_INIT), dim3(256), 0, stream, p);
  hipLaunchKernelGGL(k_mid,     dim3(NB_FACE), dim3(256), 0, stream, p);
  hipLaunchKernelGGL(k_walkall, dim3(NB_WALK), dim3(256), 0, stream, p);
  hipLaunchKernelGGL(k_tail,    dim3(NB_FB), dim3(256), 0, stream, p);
}